// Round 3
// baseline (3954.844 us; speedup 1.0000x reference)
//
#include <hip/hip_runtime.h>

#define NNODES 1000000
#define NEDGES 25000000

// ---------------------------------------------------------------------------
// Edge pass: agg[dst] += x[src]  (D=3), 4 edges per thread, vectorized index
// loads (int4), 3 f32 atomics per edge into a 12 MB accumulator in d_ws.
// ---------------------------------------------------------------------------
__global__ __launch_bounds__(256) void edge_kernel(
    const int* __restrict__ src, const int* __restrict__ dst,
    const float* __restrict__ x, float* __restrict__ agg, int e4)
{
    int i = blockIdx.x * blockDim.x + threadIdx.x;
    if (i >= e4) return;
    int4 s4 = ((const int4*)src)[i];
    int4 d4 = ((const int4*)dst)[i];
    #pragma unroll
    for (int k = 0; k < 4; ++k) {
        int s = (&s4.x)[k];
        int d = (&d4.x)[k];
        float x0 = x[s * 3 + 0];
        float x1 = x[s * 3 + 1];
        float x2 = x[s * 3 + 2];
        atomicAdd(&agg[d * 3 + 0], x0);
        atomicAdd(&agg[d * 3 + 1], x1);
        atomicAdd(&agg[d * 3 + 2], x2);
    }
}

// ---------------------------------------------------------------------------
// Node pass: h = relu(x@W + agg@M); accumulate sum over nodes into s[3].
// 4 nodes per thread via 3x float4 loads per array; wave shuffle-reduce,
// then one atomicAdd per wave per component.
// ---------------------------------------------------------------------------
__global__ __launch_bounds__(256) void node_kernel(
    const float* __restrict__ x, const float* __restrict__ agg,
    const float* __restrict__ W, const float* __restrict__ M,
    float* __restrict__ s_out)
{
    // 3x3 weights, uniform across threads (scalar-cached loads)
    float w[9], m[9];
    #pragma unroll
    for (int k = 0; k < 9; ++k) { w[k] = W[k]; m[k] = M[k]; }

    float acc0 = 0.f, acc1 = 0.f, acc2 = 0.f;

    int t = blockIdx.x * blockDim.x + threadIdx.x;   // t handles nodes 4t..4t+3
    if (t * 4 < NNODES) {
        const float4* x4 = (const float4*)x;
        const float4* a4 = (const float4*)agg;
        float xv[12], av[12];
        #pragma unroll
        for (int q = 0; q < 3; ++q) {
            float4 xx = x4[t * 3 + q];
            float4 aa = a4[t * 3 + q];
            xv[q * 4 + 0] = xx.x; xv[q * 4 + 1] = xx.y; xv[q * 4 + 2] = xx.z; xv[q * 4 + 3] = xx.w;
            av[q * 4 + 0] = aa.x; av[q * 4 + 1] = aa.y; av[q * 4 + 2] = aa.z; av[q * 4 + 3] = aa.w;
        }
        #pragma unroll
        for (int n = 0; n < 4; ++n) {
            float x0 = xv[n * 3 + 0], x1 = xv[n * 3 + 1], x2 = xv[n * 3 + 2];
            float a0 = av[n * 3 + 0], a1 = av[n * 3 + 1], a2 = av[n * 3 + 2];
            float h0 = x0 * w[0] + x1 * w[3] + x2 * w[6] + a0 * m[0] + a1 * m[3] + a2 * m[6];
            float h1 = x0 * w[1] + x1 * w[4] + x2 * w[7] + a0 * m[1] + a1 * m[4] + a2 * m[7];
            float h2 = x0 * w[2] + x1 * w[5] + x2 * w[8] + a0 * m[2] + a1 * m[5] + a2 * m[8];
            acc0 += fmaxf(h0, 0.f);
            acc1 += fmaxf(h1, 0.f);
            acc2 += fmaxf(h2, 0.f);
        }
    }

    // wave64 shuffle reduction
    #pragma unroll
    for (int off = 32; off > 0; off >>= 1) {
        acc0 += __shfl_down(acc0, off, 64);
        acc1 += __shfl_down(acc1, off, 64);
        acc2 += __shfl_down(acc2, off, 64);
    }
    if ((threadIdx.x & 63) == 0) {
        atomicAdd(&s_out[0], acc0);
        atomicAdd(&s_out[1], acc1);
        atomicAdd(&s_out[2], acc2);
    }
}

// ---------------------------------------------------------------------------
// Softmax over the 3-element global sum.
// ---------------------------------------------------------------------------
__global__ void softmax3_kernel(const float* __restrict__ s, float* __restrict__ out)
{
    float a = s[0], b = s[1], c = s[2];
    float mx = fmaxf(a, fmaxf(b, c));
    float ea = __expf(a - mx), eb = __expf(b - mx), ec = __expf(c - mx);
    float inv = 1.f / (ea + eb + ec);
    out[0] = ea * inv;
    out[1] = eb * inv;
    out[2] = ec * inv;
}

extern "C" void kernel_launch(void* const* d_in, const int* in_sizes, int n_in,
                              void* d_out, int out_size, void* d_ws, size_t ws_size,
                              hipStream_t stream)
{
    const float* x = (const float*)d_in[0];   // [N,3]
    const float* W = (const float*)d_in[1];   // [3,3]
    const float* M = (const float*)d_in[2];   // [3,3]
    const int* src = (const int*)d_in[3];     // [E]
    const int* dst = (const int*)d_in[4];     // [E]

    float* agg = (float*)d_ws;                                 // N*3 floats = 12 MB
    float* s   = (float*)((char*)d_ws + (size_t)NNODES * 3 * sizeof(float)); // 3 floats (+pad)

    // zero agg + s (harness poisons ws with 0xAA before every launch)
    hipMemsetAsync(d_ws, 0, (size_t)NNODES * 3 * sizeof(float) + 4 * sizeof(float), stream);

    const int e4 = NEDGES / 4;                 // 6,250,000 threads, 4 edges each
    edge_kernel<<<(e4 + 255) / 256, 256, 0, stream>>>(src, dst, x, agg, e4);

    const int nthreads = NNODES / 4;           // 250,000 threads, 4 nodes each
    node_kernel<<<(nthreads + 255) / 256, 256, 0, stream>>>(x, agg, W, M, s);

    softmax3_kernel<<<1, 1, 0, stream>>>(s, (float*)d_out);
}

// Round 4
// 1112.017 us; speedup vs baseline: 3.5565x; 3.5565x over previous
//
#include <hip/hip_runtime.h>

#define NNODES 1000000
#define NEDGES 25000000

// ---- binned-scatter parameters -------------------------------------------
#define BSHIFT 10                       // nodes per bucket = 1024
#define BNODES (1 << BSHIFT)            // 1024
#define NB 977                          // ceil(1e6 / 1024)
#define CAP 28672                       // per-bucket record capacity (mean 25590, +19 sigma)
#define NBLK_A 512                      // binning blocks

#define REC_BYTES ((size_t)NB * CAP * 4)            // 112,050,176
#define AGG_OFF   REC_BYTES
#define AGG_BYTES ((size_t)NNODES * 3 * 4)          // 12,000,000
#define CUR_OFF   (AGG_OFF + AGG_BYTES)
#define CUR_BYTES ((size_t)NB * 4)
#define S_OFF     (CUR_OFF + CUR_BYTES)
#define WS_NEEDED (S_OFF + 16)

// ---------------------------------------------------------------------------
// Phase A: bin edges by dst bucket. Per block: LDS histogram over its edge
// chunk, one global cursor atomicAdd per nonempty bucket, then write packed
// records ((src<<10)|dst_local) grouped by bucket.
// ---------------------------------------------------------------------------
__global__ __launch_bounds__(256) void bin_kernel(
    const int* __restrict__ src, const int* __restrict__ dst,
    unsigned* __restrict__ rec, unsigned* __restrict__ cursor)
{
    __shared__ unsigned hist[NB];
    __shared__ unsigned base[NB];
    const int tid = threadIdx.x;
    for (int b = tid; b < NB; b += 256) hist[b] = 0u;
    __syncthreads();

    const int E4 = NEDGES / 4;
    const int chunk4 = (E4 + NBLK_A - 1) / NBLK_A;
    const int beg4 = blockIdx.x * chunk4;
    const int end4 = min(beg4 + chunk4, E4);

    // pass 1: histogram of dst buckets (LDS atomics)
    for (int i = beg4 + tid; i < end4; i += 256) {
        int4 d4 = ((const int4*)dst)[i];
        atomicAdd(&hist[((unsigned)d4.x) >> BSHIFT], 1u);
        atomicAdd(&hist[((unsigned)d4.y) >> BSHIFT], 1u);
        atomicAdd(&hist[((unsigned)d4.z) >> BSHIFT], 1u);
        atomicAdd(&hist[((unsigned)d4.w) >> BSHIFT], 1u);
    }
    __syncthreads();

    // reserve global space per bucket (one device atomic per block-bucket)
    for (int b = tid; b < NB; b += 256) {
        unsigned c = hist[b];
        base[b] = c ? atomicAdd(&cursor[b], c) : 0u;
        hist[b] = 0u;                   // reuse as rank counter
    }
    __syncthreads();

    // pass 2: rank within block-bucket + scatter packed record
    for (int i = beg4 + tid; i < end4; i += 256) {
        int4 d4 = ((const int4*)dst)[i];
        int4 s4 = ((const int4*)src)[i];
        #pragma unroll
        for (int k = 0; k < 4; ++k) {
            unsigned d = (unsigned)(&d4.x)[k];
            unsigned s = (unsigned)(&s4.x)[k];
            unsigned b = d >> BSHIFT;
            unsigned r = atomicAdd(&hist[b], 1u) + base[b];
            if (r < (unsigned)CAP)      // 19-sigma headroom; guard vs corruption only
                rec[(size_t)b * CAP + r] = (s << BSHIFT) | (d & (BNODES - 1));
        }
    }
}

// ---------------------------------------------------------------------------
// Phase B: one block per bucket. Zero a 12 KB LDS slice, accumulate all the
// bucket's records with LDS float atomics (gathering x[src] -- plain cached
// reads), then flush the slice to agg coalesced.
// ---------------------------------------------------------------------------
__global__ __launch_bounds__(256) void reduce_kernel(
    const unsigned* __restrict__ rec, const unsigned* __restrict__ cursor,
    const float* __restrict__ x, float* __restrict__ agg)
{
    __shared__ float acc[BNODES * 3];   // 12 KB
    const int tid = threadIdx.x;
    const int b = blockIdx.x;
    for (int i = tid; i < BNODES * 3; i += 256) acc[i] = 0.f;
    __syncthreads();

    unsigned cnt = cursor[b];
    if (cnt > (unsigned)CAP) cnt = CAP;
    const unsigned* r0 = rec + (size_t)b * CAP;
    for (unsigned i = tid; i < cnt; i += 256) {
        unsigned u = r0[i];
        unsigned s = u >> BSHIFT;
        unsigned dl = u & (BNODES - 1);
        float x0 = x[s * 3 + 0];
        float x1 = x[s * 3 + 1];
        float x2 = x[s * 3 + 2];
        atomicAdd(&acc[dl * 3 + 0], x0);
        atomicAdd(&acc[dl * 3 + 1], x1);
        atomicAdd(&acc[dl * 3 + 2], x2);
    }
    __syncthreads();

    const int nbase = b << BSHIFT;
    for (int i = tid; i < BNODES; i += 256) {
        int node = nbase + i;
        if (node < NNODES) {
            agg[node * 3 + 0] = acc[i * 3 + 0];
            agg[node * 3 + 1] = acc[i * 3 + 1];
            agg[node * 3 + 2] = acc[i * 3 + 2];
        }
    }
}

// ---------------------------------------------------------------------------
// Fallback edge pass (known-passing): scattered global f32 atomics.
// ---------------------------------------------------------------------------
__global__ __launch_bounds__(256) void edge_kernel(
    const int* __restrict__ src, const int* __restrict__ dst,
    const float* __restrict__ x, float* __restrict__ agg, int e4)
{
    int i = blockIdx.x * blockDim.x + threadIdx.x;
    if (i >= e4) return;
    int4 s4 = ((const int4*)src)[i];
    int4 d4 = ((const int4*)dst)[i];
    #pragma unroll
    for (int k = 0; k < 4; ++k) {
        int s = (&s4.x)[k];
        int d = (&d4.x)[k];
        atomicAdd(&agg[d * 3 + 0], x[s * 3 + 0]);
        atomicAdd(&agg[d * 3 + 1], x[s * 3 + 1]);
        atomicAdd(&agg[d * 3 + 2], x[s * 3 + 2]);
    }
}

// ---------------------------------------------------------------------------
// Phase C: h = relu(x@W + agg@M); block/wave reduce into s[3].
// ---------------------------------------------------------------------------
__global__ __launch_bounds__(256) void node_kernel(
    const float* __restrict__ x, const float* __restrict__ agg,
    const float* __restrict__ W, const float* __restrict__ M,
    float* __restrict__ s_out)
{
    float w[9], m[9];
    #pragma unroll
    for (int k = 0; k < 9; ++k) { w[k] = W[k]; m[k] = M[k]; }

    float acc0 = 0.f, acc1 = 0.f, acc2 = 0.f;

    int t = blockIdx.x * blockDim.x + threadIdx.x;   // nodes 4t..4t+3
    if (t * 4 < NNODES) {
        const float4* x4 = (const float4*)x;
        const float4* a4 = (const float4*)agg;
        float xv[12], av[12];
        #pragma unroll
        for (int q = 0; q < 3; ++q) {
            float4 xx = x4[t * 3 + q];
            float4 aa = a4[t * 3 + q];
            xv[q * 4 + 0] = xx.x; xv[q * 4 + 1] = xx.y; xv[q * 4 + 2] = xx.z; xv[q * 4 + 3] = xx.w;
            av[q * 4 + 0] = aa.x; av[q * 4 + 1] = aa.y; av[q * 4 + 2] = aa.z; av[q * 4 + 3] = aa.w;
        }
        #pragma unroll
        for (int n = 0; n < 4; ++n) {
            float x0 = xv[n * 3 + 0], x1 = xv[n * 3 + 1], x2 = xv[n * 3 + 2];
            float a0 = av[n * 3 + 0], a1 = av[n * 3 + 1], a2 = av[n * 3 + 2];
            float h0 = x0 * w[0] + x1 * w[3] + x2 * w[6] + a0 * m[0] + a1 * m[3] + a2 * m[6];
            float h1 = x0 * w[1] + x1 * w[4] + x2 * w[7] + a0 * m[1] + a1 * m[4] + a2 * m[7];
            float h2 = x0 * w[2] + x1 * w[5] + x2 * w[8] + a0 * m[2] + a1 * m[5] + a2 * m[8];
            acc0 += fmaxf(h0, 0.f);
            acc1 += fmaxf(h1, 0.f);
            acc2 += fmaxf(h2, 0.f);
        }
    }

    #pragma unroll
    for (int off = 32; off > 0; off >>= 1) {
        acc0 += __shfl_down(acc0, off, 64);
        acc1 += __shfl_down(acc1, off, 64);
        acc2 += __shfl_down(acc2, off, 64);
    }
    if ((threadIdx.x & 63) == 0) {
        atomicAdd(&s_out[0], acc0);
        atomicAdd(&s_out[1], acc1);
        atomicAdd(&s_out[2], acc2);
    }
}

__global__ void softmax3_kernel(const float* __restrict__ s, float* __restrict__ out)
{
    float a = s[0], b = s[1], c = s[2];
    float mx = fmaxf(a, fmaxf(b, c));
    float ea = __expf(a - mx), eb = __expf(b - mx), ec = __expf(c - mx);
    float inv = 1.f / (ea + eb + ec);
    out[0] = ea * inv;
    out[1] = eb * inv;
    out[2] = ec * inv;
}

extern "C" void kernel_launch(void* const* d_in, const int* in_sizes, int n_in,
                              void* d_out, int out_size, void* d_ws, size_t ws_size,
                              hipStream_t stream)
{
    const float* x = (const float*)d_in[0];   // [N,3]
    const float* W = (const float*)d_in[1];   // [3,3]
    const float* M = (const float*)d_in[2];   // [3,3]
    const int* src = (const int*)d_in[3];     // [E]
    const int* dst = (const int*)d_in[4];     // [E]

    if (ws_size >= WS_NEEDED) {
        // ---- binned path ----
        unsigned* rec    = (unsigned*)d_ws;
        float*    agg    = (float*)((char*)d_ws + AGG_OFF);
        unsigned* cursor = (unsigned*)((char*)d_ws + CUR_OFF);
        float*    s      = (float*)((char*)d_ws + S_OFF);

        // zero cursors + s (4 KB)
        hipMemsetAsync((char*)d_ws + CUR_OFF, 0, CUR_BYTES + 16, stream);

        bin_kernel<<<NBLK_A, 256, 0, stream>>>(src, dst, rec, cursor);
        reduce_kernel<<<NB, 256, 0, stream>>>(rec, cursor, x, agg);

        const int nthreads = NNODES / 4;
        node_kernel<<<(nthreads + 255) / 256, 256, 0, stream>>>(x, agg, W, M, s);
        softmax3_kernel<<<1, 1, 0, stream>>>(s, (float*)d_out);
    } else {
        // ---- fallback: scattered-atomic path (known passing) ----
        float* agg = (float*)d_ws;
        float* s   = (float*)((char*)d_ws + AGG_BYTES);
        hipMemsetAsync(d_ws, 0, AGG_BYTES + 16, stream);

        const int e4 = NEDGES / 4;
        edge_kernel<<<(e4 + 255) / 256, 256, 0, stream>>>(src, dst, x, agg, e4);

        const int nthreads = NNODES / 4;
        node_kernel<<<(nthreads + 255) / 256, 256, 0, stream>>>(x, agg, W, M, s);
        softmax3_kernel<<<1, 1, 0, stream>>>(s, (float*)d_out);
    }
}

// Round 7
// 1032.971 us; speedup vs baseline: 3.8286x; 1.0765x over previous
//
#include <hip/hip_runtime.h>

#define NNODES 1000000
#define NEDGES 25000000

// ---- binned-scatter parameters -------------------------------------------
#define BSHIFT 12                       // nodes per bucket = 4096
#define BNODES (1 << BSHIFT)            // 4096
#define NB 245                          // ceil(1e6 / 4096)
#define CAP 112640                      // per-bucket capacity (mean 102041, +33 sigma)
#define NBLK_A 1024                     // binning blocks (4/CU)

#define REC_BYTES ((size_t)NB * CAP * 4)            // 110,387,200
#define AGG_OFF   REC_BYTES
#define AGG_BYTES ((size_t)NNODES * 3 * 4)          // 12,000,000
#define CUR_OFF   (AGG_OFF + AGG_BYTES)
#define CUR_BYTES ((size_t)NB * 4)
#define S_OFF     ((CUR_OFF + CUR_BYTES + 15) & ~(size_t)15)
#define WS_NEEDED (S_OFF + 16)          // ~122.4 MB (known ws >= 124 MB)

// ---------------------------------------------------------------------------
// Phase A: bin edges by dst bucket (4096 nodes/bucket). Per block: LDS
// histogram over its chunk, one global cursor atomicAdd per nonempty bucket,
// then rank+scatter packed records ((src<<12)|dst_local).
// Write frontier per XCD: 245 lines x 64B x 128 blocks ~ 2MB < 4MB L2.
// ---------------------------------------------------------------------------
__global__ __launch_bounds__(256) void bin_kernel(
    const int* __restrict__ src, const int* __restrict__ dst,
    unsigned* __restrict__ rec, unsigned* __restrict__ cursor)
{
    __shared__ unsigned hist[NB];
    __shared__ unsigned base[NB];
    const int tid = threadIdx.x;
    for (int b = tid; b < NB; b += 256) hist[b] = 0u;
    __syncthreads();

    const int E4 = NEDGES / 4;
    const int chunk4 = (E4 + NBLK_A - 1) / NBLK_A;
    const int beg4 = blockIdx.x * chunk4;
    const int end4 = min(beg4 + chunk4, E4);

    // pass 1: histogram of dst buckets (LDS atomics)
    for (int i = beg4 + tid; i < end4; i += 256) {
        int4 d4 = ((const int4*)dst)[i];
        atomicAdd(&hist[((unsigned)d4.x) >> BSHIFT], 1u);
        atomicAdd(&hist[((unsigned)d4.y) >> BSHIFT], 1u);
        atomicAdd(&hist[((unsigned)d4.z) >> BSHIFT], 1u);
        atomicAdd(&hist[((unsigned)d4.w) >> BSHIFT], 1u);
    }
    __syncthreads();

    // reserve global space per bucket (one device atomic per block-bucket)
    for (int b = tid; b < NB; b += 256) {
        unsigned c = hist[b];
        base[b] = c ? atomicAdd(&cursor[b], c) : 0u;
        hist[b] = 0u;                   // reuse as rank counter
    }
    __syncthreads();

    // pass 2: rank within block-bucket + scatter packed record
    for (int i = beg4 + tid; i < end4; i += 256) {
        int4 d4 = ((const int4*)dst)[i];
        int4 s4 = ((const int4*)src)[i];
        #pragma unroll
        for (int k = 0; k < 4; ++k) {
            unsigned d = (unsigned)(&d4.x)[k];
            unsigned s = (unsigned)(&s4.x)[k];
            unsigned b = d >> BSHIFT;
            unsigned r = atomicAdd(&hist[b], 1u) + base[b];
            if (r < (unsigned)CAP)      // 33-sigma headroom; corruption guard only
                rec[(size_t)b * CAP + r] = (s << BSHIFT) | (d & (BNODES - 1));
        }
    }
}

// ---------------------------------------------------------------------------
// Phase B: one 1024-thread block per bucket. Zero a 48 KB LDS slice,
// accumulate the bucket's records with LDS float atomics (x gather = plain
// cached reads), then flush coalesced (float4) to agg.
// ---------------------------------------------------------------------------
__global__ __launch_bounds__(1024) void reduce_kernel(
    const unsigned* __restrict__ rec, const unsigned* __restrict__ cursor,
    const float* __restrict__ x, float* __restrict__ agg)
{
    __shared__ float acc[BNODES * 3];   // 48 KB
    const int tid = threadIdx.x;
    const int b = blockIdx.x;
    for (int i = tid; i < BNODES * 3; i += 1024) acc[i] = 0.f;
    __syncthreads();

    unsigned cnt = cursor[b];
    if (cnt > (unsigned)CAP) cnt = CAP;
    const unsigned* r0 = rec + (size_t)b * CAP;
    for (unsigned i = tid; i < cnt; i += 1024) {
        unsigned u = r0[i];
        unsigned s = u >> BSHIFT;
        unsigned dl = u & (BNODES - 1);
        float x0 = x[s * 3 + 0];
        float x1 = x[s * 3 + 1];
        float x2 = x[s * 3 + 2];
        atomicAdd(&acc[dl * 3 + 0], x0);
        atomicAdd(&acc[dl * 3 + 1], x1);
        atomicAdd(&acc[dl * 3 + 2], x2);
    }
    __syncthreads();

    // coalesced flush; bucket base byte offset = b*49152 (16B aligned)
    const size_t fbase = (size_t)b * BNODES * 3;
    const int nfloat4 = BNODES * 3 / 4;             // 3072
    float4* aggv = (float4*)(agg + fbase);
    const float4* accv = (const float4*)acc;
    const int lim4 = (NNODES * 3 - (int)fbase + 3) / 4;  // clamp for last bucket
    for (int i = tid; i < nfloat4; i += 1024) {
        if (i < lim4) aggv[i] = accv[i];
    }
}

// ---------------------------------------------------------------------------
// Fallback edge pass (known-passing): scattered global f32 atomics.
// ---------------------------------------------------------------------------
__global__ __launch_bounds__(256) void edge_kernel(
    const int* __restrict__ src, const int* __restrict__ dst,
    const float* __restrict__ x, float* __restrict__ agg, int e4)
{
    int i = blockIdx.x * blockDim.x + threadIdx.x;
    if (i >= e4) return;
    int4 s4 = ((const int4*)src)[i];
    int4 d4 = ((const int4*)dst)[i];
    #pragma unroll
    for (int k = 0; k < 4; ++k) {
        int s = (&s4.x)[k];
        int d = (&d4.x)[k];
        atomicAdd(&agg[d * 3 + 0], x[s * 3 + 0]);
        atomicAdd(&agg[d * 3 + 1], x[s * 3 + 1]);
        atomicAdd(&agg[d * 3 + 2], x[s * 3 + 2]);
    }
}

// ---------------------------------------------------------------------------
// Phase C: h = relu(x@W + agg@M); block/wave reduce into s[3].
// ---------------------------------------------------------------------------
__global__ __launch_bounds__(256) void node_kernel(
    const float* __restrict__ x, const float* __restrict__ agg,
    const float* __restrict__ W, const float* __restrict__ M,
    float* __restrict__ s_out)
{
    float w[9], m[9];
    #pragma unroll
    for (int k = 0; k < 9; ++k) { w[k] = W[k]; m[k] = M[k]; }

    float acc0 = 0.f, acc1 = 0.f, acc2 = 0.f;

    int t = blockIdx.x * blockDim.x + threadIdx.x;   // nodes 4t..4t+3
    if (t * 4 < NNODES) {
        const float4* x4 = (const float4*)x;
        const float4* a4 = (const float4*)agg;
        float xv[12], av[12];
        #pragma unroll
        for (int q = 0; q < 3; ++q) {
            float4 xx = x4[t * 3 + q];
            float4 aa = a4[t * 3 + q];
            xv[q * 4 + 0] = xx.x; xv[q * 4 + 1] = xx.y; xv[q * 4 + 2] = xx.z; xv[q * 4 + 3] = xx.w;
            av[q * 4 + 0] = aa.x; av[q * 4 + 1] = aa.y; av[q * 4 + 2] = aa.z; av[q * 4 + 3] = aa.w;
        }
        #pragma unroll
        for (int n = 0; n < 4; ++n) {
            float x0 = xv[n * 3 + 0], x1 = xv[n * 3 + 1], x2 = xv[n * 3 + 2];
            float a0 = av[n * 3 + 0], a1 = av[n * 3 + 1], a2 = av[n * 3 + 2];
            float h0 = x0 * w[0] + x1 * w[3] + x2 * w[6] + a0 * m[0] + a1 * m[3] + a2 * m[6];
            float h1 = x0 * w[1] + x1 * w[4] + x2 * w[7] + a0 * m[1] + a1 * m[4] + a2 * m[7];
            float h2 = x0 * w[2] + x1 * w[5] + x2 * w[8] + a0 * m[2] + a1 * m[5] + a2 * m[8];
            acc0 += fmaxf(h0, 0.f);
            acc1 += fmaxf(h1, 0.f);
            acc2 += fmaxf(h2, 0.f);
        }
    }

    #pragma unroll
    for (int off = 32; off > 0; off >>= 1) {
        acc0 += __shfl_down(acc0, off, 64);
        acc1 += __shfl_down(acc1, off, 64);
        acc2 += __shfl_down(acc2, off, 64);
    }
    if ((threadIdx.x & 63) == 0) {
        atomicAdd(&s_out[0], acc0);
        atomicAdd(&s_out[1], acc1);
        atomicAdd(&s_out[2], acc2);
    }
}

__global__ void softmax3_kernel(const float* __restrict__ s, float* __restrict__ out)
{
    float a = s[0], b = s[1], c = s[2];
    float mx = fmaxf(a, fmaxf(b, c));
    float ea = __expf(a - mx), eb = __expf(b - mx), ec = __expf(c - mx);
    float inv = 1.f / (ea + eb + ec);
    out[0] = ea * inv;
    out[1] = eb * inv;
    out[2] = ec * inv;
}

extern "C" void kernel_launch(void* const* d_in, const int* in_sizes, int n_in,
                              void* d_out, int out_size, void* d_ws, size_t ws_size,
                              hipStream_t stream)
{
    const float* x = (const float*)d_in[0];   // [N,3]
    const float* W = (const float*)d_in[1];   // [3,3]
    const float* M = (const float*)d_in[2];   // [3,3]
    const int* src = (const int*)d_in[3];     // [E]
    const int* dst = (const int*)d_in[4];     // [E]

    if (ws_size >= WS_NEEDED) {
        // ---- binned path ----
        unsigned* rec    = (unsigned*)d_ws;
        float*    agg    = (float*)((char*)d_ws + AGG_OFF);
        unsigned* cursor = (unsigned*)((char*)d_ws + CUR_OFF);
        float*    s      = (float*)((char*)d_ws + S_OFF);

        // zero cursors + s (~1 KB)
        hipMemsetAsync((char*)d_ws + CUR_OFF, 0, (S_OFF - CUR_OFF) + 16, stream);

        bin_kernel<<<NBLK_A, 256, 0, stream>>>(src, dst, rec, cursor);
        reduce_kernel<<<NB, 1024, 0, stream>>>(rec, cursor, x, agg);

        const int nthreads = NNODES / 4;
        node_kernel<<<(nthreads + 255) / 256, 256, 0, stream>>>(x, agg, W, M, s);
        softmax3_kernel<<<1, 1, 0, stream>>>(s, (float*)d_out);
    } else {
        // ---- fallback: scattered-atomic path (known passing) ----
        float* agg = (float*)d_ws;
        float* s   = (float*)((char*)d_ws + AGG_BYTES);
        hipMemsetAsync(d_ws, 0, AGG_BYTES + 16, stream);

        const int e4 = NEDGES / 4;
        edge_kernel<<<(e4 + 255) / 256, 256, 0, stream>>>(src, dst, x, agg, e4);

        const int nthreads = NNODES / 4;
        node_kernel<<<(nthreads + 255) / 256, 256, 0, stream>>>(x, agg, W, M, s);

        softmax3_kernel<<<1, 1, 0, stream>>>(s, (float*)d_out);
    }
}